// Round 3
// baseline (639.593 us; speedup 1.0000x reference)
//
#include <hip/hip_runtime.h>
#include <hip/hip_bf16.h>

// DecoderBlock: h_t = tanh(x_t @ U + h_{t-1} @ V + b)
// BZ=256, SEQ=512, IN=HID=256. fp32 in/out.
//
// FUSED design: one WG (512 thr, 8 waves) per batch row runs the whole
// 512-step recurrence on the MFMA pipe. Both products (x_t@U and h@V) chain
// into the same 16x16x32 bf16 MFMA accumulators. With m=1 per WG, every lane
// reads identical A-frag values from LDS (broadcast) -> all 16 m-rows equal,
// epilogue reads reg 0 of the q==0 lanes. U,V are register-resident bf16
// B-frags (prep_W packs them). x rows prefetched 2 ahead; h double-buffered
// in LDS as bf16 -> ONE barrier per step. No separate GEMM, no XU traffic.

#define SEQn 512
#define HIDn 256

typedef __attribute__((ext_vector_type(4))) float  floatx4;
typedef __attribute__((ext_vector_type(8))) short  short8;
typedef __attribute__((ext_vector_type(4))) short  shortx4;

__device__ __forceinline__ short f2bf(float f) {
    __hip_bfloat16 h = __float2bfloat16(f);
    return *reinterpret_cast<short*>(&h);
}

// ---------------------------------------------------------------------------
// Pack U and V (fp32 [256][256]) into bf16 B-frag order:
// ws[((kb*4+q)*256 + col)*8 + j] = W[kb*32 + q*8 + j][col].  128 KB each.
// ---------------------------------------------------------------------------
__global__ void prep_W(const float* __restrict__ U, const float* __restrict__ V,
                       short* __restrict__ wsU, short* __restrict__ wsV) {
    int idx = blockIdx.x * 256 + threadIdx.x;   // 0..8191
    int col = idx & 255;
    int q   = (idx >> 8) & 3;
    int kb  = idx >> 10;
    int k0  = kb * 32 + q * 8;
    short8 cu, cv;
    #pragma unroll
    for (int j = 0; j < 8; j++) {
        cu[j] = f2bf(U[(size_t)(k0 + j) * 256 + col]);
        cv[j] = f2bf(V[(size_t)(k0 + j) * 256 + col]);
    }
    *(short8*)(wsU + (size_t)idx * 8) = cu;
    *(short8*)(wsV + (size_t)idx * 8) = cv;
}

// ---------------------------------------------------------------------------
// Fused recurrence. Wave w owns cols [32w, 32w+32) = n-tiles {2w, 2w+1}.
// ---------------------------------------------------------------------------
__global__ __launch_bounds__(512, 2)
void rnn_fused(const float* __restrict__ enc, const float* __restrict__ x,
               const float* __restrict__ bias,
               const short* __restrict__ wsU, const short* __restrict__ wsV,
               float* __restrict__ out)
{
    __shared__ short hb[2][HIDn];   // bf16 h, double-buffered
    __shared__ short xb[2][HIDn];   // bf16 x_t row, double-buffered

    const int tid = threadIdx.x;
    const int w   = tid >> 6;       // wave 0..7
    const int l   = tid & 63;
    const int lr  = l & 15;
    const int q   = l >> 4;
    const int b   = blockIdx.x;

    // Register-resident weight B-frags: uf/vf[kb][nt], 128 VGPRs total.
    short8 uf[8][2], vf[8][2];
    #pragma unroll
    for (int kb = 0; kb < 8; kb++)
        #pragma unroll
        for (int nt = 0; nt < 2; nt++) {
            size_t base = ((size_t)(kb * 4 + q) * 256 + 32 * w + 16 * nt + lr) * 8;
            uf[kb][nt] = *(const short8*)(wsU + base);
            vf[kb][nt] = *(const short8*)(wsV + base);
        }

    const float* xrow   = x + (size_t)b * SEQn * HIDn;
    float*       outDec = out + (size_t)65536 + (size_t)b * SEQn * HIDn;

    const float bias0 = bias[32 * w + lr];
    const float bias1 = bias[32 * w + 16 + lr];

    // init: hb[0] = bf16(enc row), xb[0] = bf16(x row 0), xr_next = x row 1
    float4 xr_next = make_float4(0.f, 0.f, 0.f, 0.f);
    if (l < 8) {
        int c0 = 32 * w + 4 * l;
        float4 h4 = *(const float4*)(enc + (size_t)b * HIDn + c0);
        *(shortx4*)&hb[0][c0] = (shortx4){f2bf(h4.x), f2bf(h4.y), f2bf(h4.z), f2bf(h4.w)};
        float4 x0 = *(const float4*)(xrow + c0);
        *(shortx4*)&xb[0][c0] = (shortx4){f2bf(x0.x), f2bf(x0.y), f2bf(x0.z), f2bf(x0.w)};
        xr_next = *(const float4*)(xrow + HIDn + c0);
    }
    __syncthreads();

    for (int t = 0; t < SEQn; t++) {
        const int cur = t & 1, nxt = cur ^ 1;

        // prefetch x row t+2 (clamped) — consumed next iteration
        float4 xr2 = xr_next;
        if (l < 8) {
            int t2 = (t + 2 < SEQn) ? t + 2 : SEQn - 1;
            xr2 = *(const float4*)(xrow + (size_t)t2 * HIDn + 32 * w + 4 * l);
        }

        // MFMA phase: acc(nt) = sum_k x_t[k]*U[k][col] + sum_k h[k]*V[k][col]
        floatx4 acc0 = (floatx4){0.f, 0.f, 0.f, 0.f};
        floatx4 acc1 = (floatx4){0.f, 0.f, 0.f, 0.f};
        const short* xp = &xb[cur][q * 8];
        const short* hp = &hb[cur][q * 8];
        #pragma unroll
        for (int kb = 0; kb < 8; kb++) {
            short8 xa = *(const short8*)(xp + kb * 32);
            short8 ha = *(const short8*)(hp + kb * 32);
            acc0 = __builtin_amdgcn_mfma_f32_16x16x32_bf16(xa, uf[kb][0], acc0, 0, 0, 0);
            acc1 = __builtin_amdgcn_mfma_f32_16x16x32_bf16(xa, uf[kb][1], acc1, 0, 0, 0);
            acc0 = __builtin_amdgcn_mfma_f32_16x16x32_bf16(ha, vf[kb][0], acc0, 0, 0, 0);
            acc1 = __builtin_amdgcn_mfma_f32_16x16x32_bf16(ha, vf[kb][1], acc1, 0, 0, 0);
        }

        // stage x_{t+1} into xb[nxt]
        if (l < 8) {
            int c0 = 32 * w + 4 * l;
            *(shortx4*)&xb[nxt][c0] =
                (shortx4){f2bf(xr_next.x), f2bf(xr_next.y), f2bf(xr_next.z), f2bf(xr_next.w)};
        }

        // epilogue: all 16 m-rows identical -> q==0 lanes, reg 0
        if (q == 0) {
            float s0 = acc0[0] + bias0;
            float s1 = acc1[0] + bias1;
            float e0 = __expf(2.f * s0);
            float e1 = __expf(2.f * s1);
            float h0 = 1.f - 2.f / (e0 + 1.f);
            float h1 = 1.f - 2.f / (e1 + 1.f);
            int c = 32 * w + lr;
            hb[nxt][c]      = f2bf(h0);
            hb[nxt][c + 16] = f2bf(h1);
            outDec[(size_t)t * HIDn + c]      = h0;   // fp32 output, full precision
            outDec[(size_t)t * HIDn + c + 16] = h1;
        }
        xr_next = xr2;
        __syncthreads();
    }

    // encoder passthrough (written last: allows d_out-as-weight-scratch fallback)
    if (tid < 64) {
        float4 e = *(const float4*)(enc + (size_t)b * HIDn + 4 * tid);
        *(float4*)(out + (size_t)b * HIDn + 4 * tid) = e;
    }
}

extern "C" void kernel_launch(void* const* d_in, const int* in_sizes, int n_in,
                              void* d_out, int out_size, void* d_ws, size_t ws_size,
                              hipStream_t stream) {
    const float* enc  = (const float*)d_in[0];   // [256,256]
    const float* x    = (const float*)d_in[1];   // [256,512,256]
    const float* U    = (const float*)d_in[2];   // [256,256]
    const float* V    = (const float*)d_in[3];   // [256,256]
    const float* bias = (const float*)d_in[4];   // [256]
    float* out = (float*)d_out;                  // 65536 + 33554432 floats

    // bf16 B-frag scratch: 128 KB (U) + 128 KB (V). Fallback: the 256 KB
    // encoder region of d_out — safe because rnn_fused reads weights at WG
    // start and writes the encoder region only after the 512-step loop.
    short *wsU, *wsV;
    if (ws_size >= 262144) {
        wsU = (short*)d_ws;
        wsV = wsU + 65536;
    } else {
        wsU = (short*)out;
        wsV = wsU + 65536;
    }

    prep_W<<<32, 256, 0, stream>>>(U, V, wsU, wsV);
    rnn_fused<<<256, 512, 0, stream>>>(enc, x, bias, wsU, wsV, out);
}